// Round 23
// baseline (726.891 us; speedup 1.0000x reference)
//
#include <hip/hip_runtime.h>

#define B 128
#define C 32
#define HH 16
#define V 4096
#define MARGIN 1e-4f

typedef __attribute__((ext_vector_type(8))) short bf16x8;
typedef __attribute__((ext_vector_type(4))) float f32x4;

// ---------------- helpers ----------------

__device__ __forceinline__ float cubicw(float t) {
    float at = fabsf(t);
    float at2 = at * at, at3 = at2 * at;
    if (at <= 1.f) return 1.25f * at3 - 2.25f * at2 + 1.f;
    if (at < 2.f)  return -0.75f * at3 + 3.75f * at2 - 6.f * at + 3.f;
    return 0.f;
}

__device__ __forceinline__ unsigned short f2bf_rne(float f) {
    unsigned int u = __float_as_uint(f);
    unsigned int r = (u + 0x7fffu + ((u >> 16) & 1u)) >> 16;
    return (unsigned short)r;
}
__device__ __forceinline__ float bf2f(unsigned short h) {
    return __uint_as_float(((unsigned int)h) << 16);
}

// ---------------- kernels ----------------

// setup: f_rest=feat, f_hat=0, c2 (fp64+fp32), stage-0 z, codebook bf16 hi/lo frag tables
__global__ void setup_kernel(const float* __restrict__ feat, float* __restrict__ f_rest,
                             float* __restrict__ f_hat, const float* __restrict__ cb,
                             double* __restrict__ c2d, float* __restrict__ c2f,
                             float* __restrict__ z0, unsigned short* __restrict__ cbh,
                             unsigned short* __restrict__ cbl) {
    int i = blockIdx.x * 256 + threadIdx.x;
    if (i < B * C * HH * HH) { f_rest[i] = feat[i]; f_hat[i] = 0.f; }
    if (i < V) {
        const float* p = cb + i * C;
        double s = 0.0;
        #pragma unroll
        for (int j = 0; j < C; ++j) { double d = (double)p[j]; s = fma(d, d, s); }
        c2d[i] = s;
        c2f[i] = (float)s;
    }
    if (i < B * C) {
        const float* p = feat + i * (HH * HH);
        float s = 0.f;
        for (int px = 0; px < HH * HH; ++px) s += p[px];
        z0[i] = s * (1.f / 256.f);
    }
    if (i < V * C) {
        int ii = i & 7, nn = (i >> 3) & 15, kb = (i >> 7) & 3, T = i >> 9;
        float val = cb[(T * 16 + nn) * C + kb * 8 + ii];
        unsigned short h = f2bf_rne(val);
        cbh[i] = h;
        cbl[i] = f2bf_rne(val - bf2f(h));
    }
}

// ---- MFMA top-2 scan v7: R21's 16-token wave (fits the 44-VGPR envelope) +
// block-shared DOUBLE-BUFFERED B-tiles in LDS: 4 waves share each 2 KB code
// tile (L2 traffic /4; per-tile loads become conflict-free ds_read_b128).
// One barrier per tile: producer(t+1) and consumer(t) use alternate buffers. ----
__global__ __launch_bounds__(256) void scan_mfma_kernel(
    const float* __restrict__ z, const unsigned short* __restrict__ cbh,
    const unsigned short* __restrict__ cbl, const float* __restrict__ c2f,
    float4* __restrict__ pk, int npx, int nseg, int nblk_tok)
{
    int tid = threadIdx.x;
    int wave = tid >> 6, lane = tid & 63;
    int tb  = blockIdx.x % nblk_tok;      // token-block: 64 tokens (4 waves x 16)
    int seg = blockIdx.x / nblk_tok;
    int cps = V / nseg;
    int total = B * npx;
    int tn = lane & 15, kb = lane >> 4;

    __shared__ alignas(16) float4 ldsB[2][128];   // [buf][0..63 hi | 64..127 lo]
    __shared__ float ldsc2[2][16];
    __shared__ float smb1[4][16 * 17];
    __shared__ float smb2[4][16 * 17];
    __shared__ int   smi1[4][16 * 17];

    // build this lane's A-fragment pair (8 VGPR)
    bf16x8 ah, al;
    {
        int tok = (tb * 4 + wave) * 16 + tn;
        int bq = tok / npx, n = tok - bq * npx;
        #pragma unroll
        for (int i = 0; i < 8; ++i) {
            float v = z[(bq * C + kb * 8 + i) * npx + n];
            unsigned short h = f2bf_rne(v);
            ah[i] = (short)h;
            al[i] = (short)f2bf_rne(v - bf2f(h));
        }
    }

    const float4* phv = reinterpret_cast<const float4*>(cbh);
    const float4* plv = reinterpret_cast<const float4*>(cbl);

    float b1[4], b2[4]; int i1[4];
    #pragma unroll
    for (int s = 0; s < 4; ++s) { b1[s] = 3e38f; b2[s] = 3e38f; i1[s] = 0; }

    int T0 = seg * (cps >> 4), nT = cps >> 4;

    // stage tile 0 into buffer 0
    if (tid < 64)       ldsB[0][tid]       = phv[(size_t)T0 * 64 + tid];
    else if (tid < 128) ldsB[0][tid]       = plv[(size_t)T0 * 64 + (tid - 64)];
    else if (tid < 144) ldsc2[0][tid - 128] = c2f[T0 * 16 + (tid - 128)];
    __syncthreads();

    #pragma unroll 1
    for (int t = 0; t < nT; ++t) {
        int cur = t & 1, nxt = cur ^ 1;
        if (t + 1 < nT) {
            int Tn = T0 + t + 1;
            if (tid < 64)       ldsB[nxt][tid]        = phv[(size_t)Tn * 64 + tid];
            else if (tid < 128) ldsB[nxt][tid]        = plv[(size_t)Tn * 64 + (tid - 64)];
            else if (tid < 144) ldsc2[nxt][tid - 128] = c2f[Tn * 16 + (tid - 128)];
        }

        bf16x8 bh = *reinterpret_cast<const bf16x8*>(&ldsB[cur][lane]);
        bf16x8 bl = *reinterpret_cast<const bf16x8*>(&ldsB[cur][64 + lane]);
        float c2v = ldsc2[cur][tn];

        f32x4 a0 = {0.f, 0.f, 0.f, 0.f};
        a0 = __builtin_amdgcn_mfma_f32_16x16x32_bf16(ah, bh, a0, 0, 0, 0);
        a0 = __builtin_amdgcn_mfma_f32_16x16x32_bf16(al, bh, a0, 0, 0, 0);
        a0 = __builtin_amdgcn_mfma_f32_16x16x32_bf16(ah, bl, a0, 0, 0, 0);
        a0 = __builtin_amdgcn_mfma_f32_16x16x32_bf16(al, bl, a0, 0, 0, 0);

        int code = (T0 + t) * 16 + tn;   // ascending with t -> strict < keeps lowest idx
        #pragma unroll
        for (int r = 0; r < 4; ++r) {
            float s0 = fmaf(-2.f, a0[r], c2v);
            if (s0 < b1[r]) { b2[r] = b1[r]; b1[r] = s0; i1[r] = code; }
            else if (s0 < b2[r]) { b2[r] = s0; }
        }
        __syncthreads();   // separates tile t reads from tile t+2 stage writes
    }

    // lane holds top-2 for tokens kb*4+r (codes === tn mod 16)
    #pragma unroll
    for (int r = 0; r < 4; ++r) {
        int tokl = kb * 4 + r;
        smb1[wave][tokl * 17 + tn] = b1[r];
        smb2[wave][tokl * 17 + tn] = b2[r];
        smi1[wave][tokl * 17 + tn] = i1[r];
    }
    __syncthreads();
    if (tid < 64) {
        int w = tid >> 4, tl = tid & 15;
        float gb1 = 3e38f, gb2 = 3e38f; int gi1 = 0;
        #pragma unroll
        for (int i = 0; i < 16; ++i) {
            float v1 = smb1[w][tl * 17 + i];
            int   ix = smi1[w][tl * 17 + i];
            if (v1 < gb1 || (v1 == gb1 && ix < gi1)) { gb2 = gb1; gb1 = v1; gi1 = ix; }
            else if (v1 < gb2) { gb2 = v1; }
            float v2 = smb2[w][tl * 17 + i];
            if (v2 < gb2) gb2 = v2;
        }
        int tok = (tb * 4 + w) * 16 + tl;
        float4 o;
        o.x = gb1; o.y = gb2; o.z = __int_as_float(gi1); o.w = 0.f;
        pk[(size_t)seg * total + tok] = o;
    }
}

// fused tail v4 (R21 exact, best-known): w staged in LDS early; packed 16B combine
// loads; 16-channel bicubic chunks.  B*4 blocks, 8 out-ch each.
__global__ __launch_bounds__(256) void stage_tail_kernel(
    const float4* __restrict__ pk, const float* __restrict__ z,
    const float* __restrict__ cb, const double* __restrict__ c2d,
    const float* __restrict__ w, const float* __restrict__ bias,
    float* __restrict__ f_hat, float* __restrict__ f_rest,
    float* __restrict__ out, float* __restrict__ znext,
    int pn, int off, int pn2, int nseg)
{
    int bb = blockIdx.x >> 2;
    int og = (blockIdx.x & 3) * 8;
    int tid = threadIdx.x;
    int npx = pn * pn;
    int total = B * npx;

    __shared__ float A_s[32][257];
    __shared__ float Bc[16][257];
    __shared__ alignas(16) float w_s[8 * 384];
    __shared__ int idx_s[256];
    __shared__ int flist[256];
    __shared__ int fcnt;
    __shared__ double zsd[C];
    __shared__ double sred[256];
    __shared__ int sidx[256];
    __shared__ float wtab[16][4];
    __shared__ int   itab[16][4];
    float (*fh_s)[257] = &A_s[0];
    float (*fr_s)[257] = &A_s[8];

    float pf[8], pr[8];
    #pragma unroll
    for (int o = 0; o < 8; ++o) {
        int gi = (bb * 32 + og + o) * 256 + tid;
        pf[o] = f_hat[gi]; pr[o] = f_rest[gi];
    }
    for (int e = tid; e < 8 * 288; e += 256) {
        int o = e / 288, r = e - o * 288;
        w_s[o * 384 + (r / 9) * 12 + (r % 9)] = w[(size_t)og * 288 + e];
    }

    if (tid < 16) {
        float scale = (float)pn * (1.f / 16.f);
        float src = (tid + 0.5f) * scale - 0.5f;
        int fi = (int)floorf(src);
        float t = src - (float)fi;
        #pragma unroll
        for (int k = 0; k < 4; ++k) {
            wtab[tid][k] = cubicw((float)(k - 1) - t);
            itab[tid][k] = min(max(fi + k - 1, 0), pn - 1);
        }
    }
    if (tid == 0) fcnt = 0;
    __syncthreads();

    if (tid < npx) {
        int tok = bb * npx + tid;
        float gb1 = 3e38f, gb2 = 3e38f; int gi1 = 0;
        for (int s = 0; s < nseg; ++s) {
            float4 e = pk[(size_t)s * total + tok];
            float v1 = e.x; int ix = __float_as_int(e.z);
            if (v1 < gb1 || (v1 == gb1 && ix < gi1)) { gb2 = gb1; gb1 = v1; gi1 = ix; }
            else if (v1 < gb2) { gb2 = v1; }
            if (e.y < gb2) gb2 = e.y;
        }
        idx_s[tid] = gi1;
        if (gb2 - gb1 < MARGIN) { int slot = atomicAdd(&fcnt, 1); flist[slot] = tid; }
    }
    __syncthreads();

    int nf = fcnt;
    for (int f = 0; f < nf; ++f) {
        int n = flist[f];
        if (tid < C) zsd[tid] = (double)z[(bb * C + tid) * npx + n];
        __syncthreads();
        double best = 1e300; int bi = 0x7fffffff;
        for (int k = 0; k < V / 256; ++k) {
            int v = tid + k * 256;
            const float4* cp = reinterpret_cast<const float4*>(cb + (size_t)v * C);
            double acc = 0.0;
            #pragma unroll
            for (int qq = 0; qq < 8; ++qq) {
                float4 fv = cp[qq];
                acc = fma((double)fv.x, zsd[4 * qq + 0], acc);
                acc = fma((double)fv.y, zsd[4 * qq + 1], acc);
                acc = fma((double)fv.z, zsd[4 * qq + 2], acc);
                acc = fma((double)fv.w, zsd[4 * qq + 3], acc);
            }
            double s = fma(-2.0, acc, c2d[v]);
            if (s < best || (s == best && v < bi)) { best = s; bi = v; }
        }
        sred[tid] = best; sidx[tid] = bi;
        __syncthreads();
        for (int st = 128; st > 0; st >>= 1) {
            if (tid < st) {
                double o = sred[tid + st]; int oi = sidx[tid + st];
                double me = sred[tid];     int mi = sidx[tid];
                if (o < me || (o == me && oi < mi)) { sred[tid] = o; sidx[tid] = oi; }
            }
            __syncthreads();
        }
        if (tid == 0) idx_s[n] = sidx[0];
        __syncthreads();
    }
    __syncthreads();

    for (int e = tid; e < 32 * npx; e += 256) {
        int c = e & 31, n = e >> 5;
        A_s[c][n] = cb[idx_s[n] * 32 + c];
    }
    __syncthreads();

    #pragma unroll 1
    for (int ch = 0; ch < 2; ++ch) {
        for (int e = tid; e < 16 * 16 * pn; e += 256) {
            int wx = e % pn; int rest = e / pn;
            int p = rest & 15, cl = rest >> 4;
            float s = 0.f;
            #pragma unroll
            for (int k = 0; k < 4; ++k)
                s = fmaf(wtab[p][k], A_s[ch * 16 + cl][itab[p][k] * pn + wx], s);
            Bc[cl][p * pn + wx] = s;
        }
        __syncthreads();
        #pragma unroll
        for (int it = 0; it < 16; ++it) {
            int e = tid + it * 256;
            int q = e & 15, p = (e >> 4) & 15, cl = e >> 8;
            float s = 0.f;
            #pragma unroll
            for (int k = 0; k < 4; ++k)
                s = fmaf(wtab[q][k], Bc[cl][p * pn + itab[q][k]], s);
            A_s[ch * 16 + cl][e & 255] = s;
        }
        __syncthreads();
    }

    int p = tid >> 4, q = tid & 15;
    float acc[8];
    #pragma unroll
    for (int o = 0; o < 8; ++o) acc[o] = bias[og + o];
    for (int i = 0; i < 32; ++i) {
        float v[9];
        #pragma unroll
        for (int dy = 0; dy < 3; ++dy)
            #pragma unroll
            for (int dx = 0; dx < 3; ++dx) {
                int pp = p + dy - 1, qq = q + dx - 1;
                bool in = (pp >= 0) & (pp < 16) & (qq >= 0) & (qq < 16);
                v[dy * 3 + dx] = in ? A_s[i][pp * 16 + qq] : 0.f;
            }
        #pragma unroll
        for (int o = 0; o < 8; ++o) {
            const float* wr = &w_s[o * 384 + i * 12];
            float4 wa = *reinterpret_cast<const float4*>(wr);
            float4 wb = *reinterpret_cast<const float4*>(wr + 4);
            float w8 = wr[8];
            acc[o] = fmaf(wa.x, v[0], acc[o]); acc[o] = fmaf(wa.y, v[1], acc[o]);
            acc[o] = fmaf(wa.z, v[2], acc[o]); acc[o] = fmaf(wa.w, v[3], acc[o]);
            acc[o] = fmaf(wb.x, v[4], acc[o]); acc[o] = fmaf(wb.y, v[5], acc[o]);
            acc[o] = fmaf(wb.z, v[6], acc[o]); acc[o] = fmaf(wb.w, v[7], acc[o]);
            acc[o] = fmaf(w8,   v[8], acc[o]);
        }
    }
    float hv[8];
    #pragma unroll
    for (int o = 0; o < 8; ++o) hv[o] = A_s[og + o][tid];
    __syncthreads();

    #pragma unroll
    for (int o = 0; o < 8; ++o) {
        int gi = (bb * 32 + og + o) * 256 + tid;
        float blend = 0.5f * hv[o] + 0.5f * acc[o];
        float nf2 = pf[o] + blend;
        float nr2 = pr[o] - blend;
        f_hat[gi] = nf2; f_rest[gi] = nr2;
        fh_s[o][tid] = nf2; fr_s[o][tid] = nr2;
    }
    __syncthreads();

    for (int e = tid; e < 8 * npx; e += 256) {
        int o = e & 7, n = e >> 3;
        int y = n / pn, x = n - y * pn;
        int sh = (y * HH) / pn, eh = ((y + 1) * HH + pn - 1) / pn;
        int sw = (x * HH) / pn, ew = ((x + 1) * HH + pn - 1) / pn;
        float s = 0.f;
        for (int yy = sh; yy < eh; ++yy)
            for (int xx = sw; xx < ew; ++xx) s += fh_s[o][yy * 16 + xx];
        out[((bb * 680) + off + n) * 32 + og + o] = s * (1.f / (float)((eh - sh) * (ew - sw)));
    }

    if (pn2 > 0) {
        int npx2 = pn2 * pn2;
        for (int e = tid; e < 8 * npx2; e += 256) {
            int o = e / npx2, n = e - o * npx2;
            int y = n / pn2, x = n - y * pn2;
            int sh = (y * HH) / pn2, eh = ((y + 1) * HH + pn2 - 1) / pn2;
            int sw = (x * HH) / pn2, ew = ((x + 1) * HH + pn2 - 1) / pn2;
            float s = 0.f;
            for (int yy = sh; yy < eh; ++yy)
                for (int xx = sw; xx < ew; ++xx) s += fr_s[o][yy * 16 + xx];
            znext[(bb * 32 + og + o) * npx2 + n] = s * (1.f / (float)((eh - sh) * (ew - sw)));
        }
    }
}

// ---------------- launch ----------------

extern "C" void kernel_launch(void* const* d_in, const int* in_sizes, int n_in,
                              void* d_out, int out_size, void* d_ws, size_t ws_size,
                              hipStream_t stream) {
    const float* feat = (const float*)d_in[0];
    const float* cb   = (const float*)d_in[1];
    const float* phiw = (const float*)d_in[2];
    const float* phib = (const float*)d_in[3];
    float* out = (float*)d_out;
    float* wsf = (float*)d_ws;

    const int NE = B * C * HH * HH; // 1048576
    float* f_rest = wsf;
    float* f_hat  = wsf + NE;
    float* zA     = wsf + 2 * NE;
    float* zB     = wsf + 3 * NE;
    char*  tl     = (char*)(wsf + 4 * NE);
    double* c2d  = (double*)tl;                             // 32 KB
    float*  c2f  = (float*)(tl + (32 << 10));               // 16 KB
    float4* pk   = (float4*)(tl + (48 << 10));              // 4 MB
    unsigned short* cbh = (unsigned short*)(tl + (48 << 10) + (4 << 20));   // 256 KB
    unsigned short* cbl = (unsigned short*)(tl + (48 << 10) + (4 << 20) + (512 << 10));

    static const int PN_[10]   = {1, 2, 3, 4, 5, 6, 8, 10, 13, 16};
    static const int PI_[10]   = {0, 0, 1, 1, 1, 2, 2, 2, 3, 3};
    static const int OFF_[10]  = {0, 1, 5, 14, 30, 55, 91, 155, 255, 424};
    static const int NSEG_[10] = {32, 32, 32, 32, 16, 16, 8, 8, 4, 4};

    setup_kernel<<<dim3((NE + 255) / 256), dim3(256), 0, stream>>>(
        feat, f_rest, f_hat, cb, c2d, c2f, zA, cbh, cbl);

    for (int si = 0; si < 10; ++si) {
        int pn = PN_[si], npx = pn * pn;
        int tokens = B * npx;            // divisible by 64 at every stage
        int nseg = NSEG_[si];
        int nblk_tok = tokens / 64;      // 64 tokens per block (4 waves x 16)
        int nblk = nblk_tok * nseg;
        float* zin  = (si & 1) ? zB : zA;
        float* zout = (si & 1) ? zA : zB;

        scan_mfma_kernel<<<dim3(nblk), dim3(256), 0, stream>>>(
            zin, cbh, cbl, c2f, pk, npx, nseg, nblk_tok);

        int pn2 = (si < 9) ? PN_[si + 1] : 0;
        stage_tail_kernel<<<dim3(B * 4), dim3(256), 0, stream>>>(
            pk, zin, cb, c2d,
            phiw + PI_[si] * C * C * 9, phib + PI_[si] * C,
            f_hat, f_rest, out, zout, pn, OFF_[si], pn2, nseg);
    }
}

// Round 24
// 697.183 us; speedup vs baseline: 1.0426x; 1.0426x over previous
//
#include <hip/hip_runtime.h>

#define B 128
#define C 32
#define HH 16
#define V 4096
#define MARGIN 1e-4f

typedef __attribute__((ext_vector_type(8))) short bf16x8;
typedef __attribute__((ext_vector_type(4))) float f32x4;

// ---------------- helpers ----------------

__device__ __forceinline__ float cubicw(float t) {
    float at = fabsf(t);
    float at2 = at * at, at3 = at2 * at;
    if (at <= 1.f) return 1.25f * at3 - 2.25f * at2 + 1.f;
    if (at < 2.f)  return -0.75f * at3 + 3.75f * at2 - 6.f * at + 3.f;
    return 0.f;
}

__device__ __forceinline__ unsigned short f2bf_rne(float f) {
    unsigned int u = __float_as_uint(f);
    unsigned int r = (u + 0x7fffu + ((u >> 16) & 1u)) >> 16;
    return (unsigned short)r;
}
__device__ __forceinline__ float bf2f(unsigned short h) {
    return __uint_as_float(((unsigned int)h) << 16);
}

// ---------------- kernels ----------------

// setup: f_rest=feat, f_hat=0, c2 (fp64+fp32), stage-0 z, codebook bf16 hi/lo frag tables
__global__ void setup_kernel(const float* __restrict__ feat, float* __restrict__ f_rest,
                             float* __restrict__ f_hat, const float* __restrict__ cb,
                             double* __restrict__ c2d, float* __restrict__ c2f,
                             float* __restrict__ z0, unsigned short* __restrict__ cbh,
                             unsigned short* __restrict__ cbl) {
    int i = blockIdx.x * 256 + threadIdx.x;
    if (i < B * C * HH * HH) { f_rest[i] = feat[i]; f_hat[i] = 0.f; }
    if (i < V) {
        const float* p = cb + i * C;
        double s = 0.0;
        #pragma unroll
        for (int j = 0; j < C; ++j) { double d = (double)p[j]; s = fma(d, d, s); }
        c2d[i] = s;
        c2f[i] = (float)s;
    }
    if (i < B * C) {
        const float* p = feat + i * (HH * HH);
        float s = 0.f;
        for (int px = 0; px < HH * HH; ++px) s += p[px];
        z0[i] = s * (1.f / 256.f);
    }
    if (i < V * C) {
        int ii = i & 7, nn = (i >> 3) & 15, kb = (i >> 7) & 3, T = i >> 9;
        float val = cb[(T * 16 + nn) * C + kb * 8 + ii];
        unsigned short h = f2bf_rne(val);
        cbh[i] = h;
        cbl[i] = f2bf_rne(val - bf2f(h));
    }
}

// ---- MFMA top-2 scan v8: 16-token waves (R21 envelope) + block-shared B-tiles
// staged in GROUPS OF 4, double-buffered: barriers /4 per work vs R23 (8/job at
// nseg=8), L2 traffic /4 vs R21 (4 waves share each 2 KB tile), all 256 threads
// stage.  R23's per-tile barrier (256/job) ate the gain; this amortizes it. ----
__global__ __launch_bounds__(256) void scan_mfma_kernel(
    const float* __restrict__ z, const unsigned short* __restrict__ cbh,
    const unsigned short* __restrict__ cbl, const float* __restrict__ c2f,
    float4* __restrict__ pk, int npx, int nseg, int nblk_tok)
{
    int tid = threadIdx.x;
    int wave = tid >> 6, lane = tid & 63;
    int tb  = blockIdx.x % nblk_tok;      // token-block: 64 tokens (4 waves x 16)
    int seg = blockIdx.x / nblk_tok;
    int cps = V / nseg;
    int total = B * npx;
    int tn = lane & 15, kb = lane >> 4;

    __shared__ alignas(16) float4 ldsB[2][4][128];   // [buf][tile][0..63 hi | 64..127 lo]
    __shared__ float ldsc2[2][4][16];
    __shared__ float smb1[4][16 * 17];
    __shared__ float smb2[4][16 * 17];
    __shared__ int   smi1[4][16 * 17];

    // build this lane's A-fragment pair (8 VGPR)
    bf16x8 ah, al;
    {
        int tok = (tb * 4 + wave) * 16 + tn;
        int bq = tok / npx, n = tok - bq * npx;
        #pragma unroll
        for (int i = 0; i < 8; ++i) {
            float v = z[(bq * C + kb * 8 + i) * npx + n];
            unsigned short h = f2bf_rne(v);
            ah[i] = (short)h;
            al[i] = (short)f2bf_rne(v - bf2f(h));
        }
    }

    const float4* phv = reinterpret_cast<const float4*>(cbh);
    const float4* plv = reinterpret_cast<const float4*>(cbl);

    float b1[4], b2[4]; int i1[4];
    #pragma unroll
    for (int s = 0; s < 4; ++s) { b1[s] = 3e38f; b2[s] = 3e38f; i1[s] = 0; }

    int T0 = seg * (cps >> 4), nT = cps >> 4;   // nT divisible by 4 at every stage
    int nG = nT >> 2;

    // stage group 0 into buffer 0 (all 256 threads; per-wave-uniform hi/lo branch)
    {
        #pragma unroll
        for (int k = 0; k < 2; ++k) {
            int e = tid + k * 256;
            int tl = e >> 7, idx = e & 127;
            int T = T0 + tl;
            ldsB[0][tl][idx] = (idx < 64) ? phv[(size_t)T * 64 + idx]
                                          : plv[(size_t)T * 64 + (idx - 64)];
        }
        if (tid < 64) ldsc2[0][tid >> 4][tid & 15] = c2f[(T0 + (tid >> 4)) * 16 + (tid & 15)];
    }
    __syncthreads();

    #pragma unroll 1
    for (int g = 0; g < nG; ++g) {
        int cur = g & 1;
        if (g + 1 < nG) {
            int Tb = T0 + (g + 1) * 4;
            int nxt = cur ^ 1;
            #pragma unroll
            for (int k = 0; k < 2; ++k) {
                int e = tid + k * 256;
                int tl = e >> 7, idx = e & 127;
                int T = Tb + tl;
                ldsB[nxt][tl][idx] = (idx < 64) ? phv[(size_t)T * 64 + idx]
                                                : plv[(size_t)T * 64 + (idx - 64)];
            }
            if (tid < 64) ldsc2[nxt][tid >> 4][tid & 15] = c2f[(Tb + (tid >> 4)) * 16 + (tid & 15)];
        }

        #pragma unroll
        for (int tt = 0; tt < 4; ++tt) {
            bf16x8 bh = *reinterpret_cast<const bf16x8*>(&ldsB[cur][tt][lane]);
            bf16x8 bl = *reinterpret_cast<const bf16x8*>(&ldsB[cur][tt][64 + lane]);
            float c2v = ldsc2[cur][tt][tn];

            f32x4 a0 = {0.f, 0.f, 0.f, 0.f};
            a0 = __builtin_amdgcn_mfma_f32_16x16x32_bf16(ah, bh, a0, 0, 0, 0);
            a0 = __builtin_amdgcn_mfma_f32_16x16x32_bf16(al, bh, a0, 0, 0, 0);
            a0 = __builtin_amdgcn_mfma_f32_16x16x32_bf16(ah, bl, a0, 0, 0, 0);
            a0 = __builtin_amdgcn_mfma_f32_16x16x32_bf16(al, bl, a0, 0, 0, 0);

            int code = (T0 + g * 4 + tt) * 16 + tn;   // ascending -> strict < keeps lowest idx
            #pragma unroll
            for (int r = 0; r < 4; ++r) {
                float s0 = fmaf(-2.f, a0[r], c2v);
                if (s0 < b1[r]) { b2[r] = b1[r]; b1[r] = s0; i1[r] = code; }
                else if (s0 < b2[r]) { b2[r] = s0; }
            }
        }
        __syncthreads();   // reads of cur done before next iteration overwrites it
    }

    // lane holds top-2 for tokens kb*4+r (codes === tn mod 16)
    #pragma unroll
    for (int r = 0; r < 4; ++r) {
        int tokl = kb * 4 + r;
        smb1[wave][tokl * 17 + tn] = b1[r];
        smb2[wave][tokl * 17 + tn] = b2[r];
        smi1[wave][tokl * 17 + tn] = i1[r];
    }
    __syncthreads();
    if (tid < 64) {
        int w = tid >> 4, tl = tid & 15;
        float gb1 = 3e38f, gb2 = 3e38f; int gi1 = 0;
        #pragma unroll
        for (int i = 0; i < 16; ++i) {
            float v1 = smb1[w][tl * 17 + i];
            int   ix = smi1[w][tl * 17 + i];
            if (v1 < gb1 || (v1 == gb1 && ix < gi1)) { gb2 = gb1; gb1 = v1; gi1 = ix; }
            else if (v1 < gb2) { gb2 = v1; }
            float v2 = smb2[w][tl * 17 + i];
            if (v2 < gb2) gb2 = v2;
        }
        int tok = (tb * 4 + w) * 16 + tl;
        float4 o;
        o.x = gb1; o.y = gb2; o.z = __int_as_float(gi1); o.w = 0.f;
        pk[(size_t)seg * total + tok] = o;
    }
}

// fused tail v4 (R21 exact, best-known): w staged in LDS early; packed 16B combine
// loads; 16-channel bicubic chunks.  B*4 blocks, 8 out-ch each.
__global__ __launch_bounds__(256) void stage_tail_kernel(
    const float4* __restrict__ pk, const float* __restrict__ z,
    const float* __restrict__ cb, const double* __restrict__ c2d,
    const float* __restrict__ w, const float* __restrict__ bias,
    float* __restrict__ f_hat, float* __restrict__ f_rest,
    float* __restrict__ out, float* __restrict__ znext,
    int pn, int off, int pn2, int nseg)
{
    int bb = blockIdx.x >> 2;
    int og = (blockIdx.x & 3) * 8;
    int tid = threadIdx.x;
    int npx = pn * pn;
    int total = B * npx;

    __shared__ float A_s[32][257];
    __shared__ float Bc[16][257];
    __shared__ alignas(16) float w_s[8 * 384];
    __shared__ int idx_s[256];
    __shared__ int flist[256];
    __shared__ int fcnt;
    __shared__ double zsd[C];
    __shared__ double sred[256];
    __shared__ int sidx[256];
    __shared__ float wtab[16][4];
    __shared__ int   itab[16][4];
    float (*fh_s)[257] = &A_s[0];
    float (*fr_s)[257] = &A_s[8];

    float pf[8], pr[8];
    #pragma unroll
    for (int o = 0; o < 8; ++o) {
        int gi = (bb * 32 + og + o) * 256 + tid;
        pf[o] = f_hat[gi]; pr[o] = f_rest[gi];
    }
    for (int e = tid; e < 8 * 288; e += 256) {
        int o = e / 288, r = e - o * 288;
        w_s[o * 384 + (r / 9) * 12 + (r % 9)] = w[(size_t)og * 288 + e];
    }

    if (tid < 16) {
        float scale = (float)pn * (1.f / 16.f);
        float src = (tid + 0.5f) * scale - 0.5f;
        int fi = (int)floorf(src);
        float t = src - (float)fi;
        #pragma unroll
        for (int k = 0; k < 4; ++k) {
            wtab[tid][k] = cubicw((float)(k - 1) - t);
            itab[tid][k] = min(max(fi + k - 1, 0), pn - 1);
        }
    }
    if (tid == 0) fcnt = 0;
    __syncthreads();

    if (tid < npx) {
        int tok = bb * npx + tid;
        float gb1 = 3e38f, gb2 = 3e38f; int gi1 = 0;
        for (int s = 0; s < nseg; ++s) {
            float4 e = pk[(size_t)s * total + tok];
            float v1 = e.x; int ix = __float_as_int(e.z);
            if (v1 < gb1 || (v1 == gb1 && ix < gi1)) { gb2 = gb1; gb1 = v1; gi1 = ix; }
            else if (v1 < gb2) { gb2 = v1; }
            if (e.y < gb2) gb2 = e.y;
        }
        idx_s[tid] = gi1;
        if (gb2 - gb1 < MARGIN) { int slot = atomicAdd(&fcnt, 1); flist[slot] = tid; }
    }
    __syncthreads();

    int nf = fcnt;
    for (int f = 0; f < nf; ++f) {
        int n = flist[f];
        if (tid < C) zsd[tid] = (double)z[(bb * C + tid) * npx + n];
        __syncthreads();
        double best = 1e300; int bi = 0x7fffffff;
        for (int k = 0; k < V / 256; ++k) {
            int v = tid + k * 256;
            const float4* cp = reinterpret_cast<const float4*>(cb + (size_t)v * C);
            double acc = 0.0;
            #pragma unroll
            for (int qq = 0; qq < 8; ++qq) {
                float4 fv = cp[qq];
                acc = fma((double)fv.x, zsd[4 * qq + 0], acc);
                acc = fma((double)fv.y, zsd[4 * qq + 1], acc);
                acc = fma((double)fv.z, zsd[4 * qq + 2], acc);
                acc = fma((double)fv.w, zsd[4 * qq + 3], acc);
            }
            double s = fma(-2.0, acc, c2d[v]);
            if (s < best || (s == best && v < bi)) { best = s; bi = v; }
        }
        sred[tid] = best; sidx[tid] = bi;
        __syncthreads();
        for (int st = 128; st > 0; st >>= 1) {
            if (tid < st) {
                double o = sred[tid + st]; int oi = sidx[tid + st];
                double me = sred[tid];     int mi = sidx[tid];
                if (o < me || (o == me && oi < mi)) { sred[tid] = o; sidx[tid] = oi; }
            }
            __syncthreads();
        }
        if (tid == 0) idx_s[n] = sidx[0];
        __syncthreads();
    }
    __syncthreads();

    for (int e = tid; e < 32 * npx; e += 256) {
        int c = e & 31, n = e >> 5;
        A_s[c][n] = cb[idx_s[n] * 32 + c];
    }
    __syncthreads();

    #pragma unroll 1
    for (int ch = 0; ch < 2; ++ch) {
        for (int e = tid; e < 16 * 16 * pn; e += 256) {
            int wx = e % pn; int rest = e / pn;
            int p = rest & 15, cl = rest >> 4;
            float s = 0.f;
            #pragma unroll
            for (int k = 0; k < 4; ++k)
                s = fmaf(wtab[p][k], A_s[ch * 16 + cl][itab[p][k] * pn + wx], s);
            Bc[cl][p * pn + wx] = s;
        }
        __syncthreads();
        #pragma unroll
        for (int it = 0; it < 16; ++it) {
            int e = tid + it * 256;
            int q = e & 15, p = (e >> 4) & 15, cl = e >> 8;
            float s = 0.f;
            #pragma unroll
            for (int k = 0; k < 4; ++k)
                s = fmaf(wtab[q][k], Bc[cl][p * pn + itab[q][k]], s);
            A_s[ch * 16 + cl][e & 255] = s;
        }
        __syncthreads();
    }

    int p = tid >> 4, q = tid & 15;
    float acc[8];
    #pragma unroll
    for (int o = 0; o < 8; ++o) acc[o] = bias[og + o];
    for (int i = 0; i < 32; ++i) {
        float v[9];
        #pragma unroll
        for (int dy = 0; dy < 3; ++dy)
            #pragma unroll
            for (int dx = 0; dx < 3; ++dx) {
                int pp = p + dy - 1, qq = q + dx - 1;
                bool in = (pp >= 0) & (pp < 16) & (qq >= 0) & (qq < 16);
                v[dy * 3 + dx] = in ? A_s[i][pp * 16 + qq] : 0.f;
            }
        #pragma unroll
        for (int o = 0; o < 8; ++o) {
            const float* wr = &w_s[o * 384 + i * 12];
            float4 wa = *reinterpret_cast<const float4*>(wr);
            float4 wb = *reinterpret_cast<const float4*>(wr + 4);
            float w8 = wr[8];
            acc[o] = fmaf(wa.x, v[0], acc[o]); acc[o] = fmaf(wa.y, v[1], acc[o]);
            acc[o] = fmaf(wa.z, v[2], acc[o]); acc[o] = fmaf(wa.w, v[3], acc[o]);
            acc[o] = fmaf(wb.x, v[4], acc[o]); acc[o] = fmaf(wb.y, v[5], acc[o]);
            acc[o] = fmaf(wb.z, v[6], acc[o]); acc[o] = fmaf(wb.w, v[7], acc[o]);
            acc[o] = fmaf(w8,   v[8], acc[o]);
        }
    }
    float hv[8];
    #pragma unroll
    for (int o = 0; o < 8; ++o) hv[o] = A_s[og + o][tid];
    __syncthreads();

    #pragma unroll
    for (int o = 0; o < 8; ++o) {
        int gi = (bb * 32 + og + o) * 256 + tid;
        float blend = 0.5f * hv[o] + 0.5f * acc[o];
        float nf2 = pf[o] + blend;
        float nr2 = pr[o] - blend;
        f_hat[gi] = nf2; f_rest[gi] = nr2;
        fh_s[o][tid] = nf2; fr_s[o][tid] = nr2;
    }
    __syncthreads();

    for (int e = tid; e < 8 * npx; e += 256) {
        int o = e & 7, n = e >> 3;
        int y = n / pn, x = n - y * pn;
        int sh = (y * HH) / pn, eh = ((y + 1) * HH + pn - 1) / pn;
        int sw = (x * HH) / pn, ew = ((x + 1) * HH + pn - 1) / pn;
        float s = 0.f;
        for (int yy = sh; yy < eh; ++yy)
            for (int xx = sw; xx < ew; ++xx) s += fh_s[o][yy * 16 + xx];
        out[((bb * 680) + off + n) * 32 + og + o] = s * (1.f / (float)((eh - sh) * (ew - sw)));
    }

    if (pn2 > 0) {
        int npx2 = pn2 * pn2;
        for (int e = tid; e < 8 * npx2; e += 256) {
            int o = e / npx2, n = e - o * npx2;
            int y = n / pn2, x = n - y * pn2;
            int sh = (y * HH) / pn2, eh = ((y + 1) * HH + pn2 - 1) / pn2;
            int sw = (x * HH) / pn2, ew = ((x + 1) * HH + pn2 - 1) / pn2;
            float s = 0.f;
            for (int yy = sh; yy < eh; ++yy)
                for (int xx = sw; xx < ew; ++xx) s += fr_s[o][yy * 16 + xx];
            znext[(bb * 32 + og + o) * npx2 + n] = s * (1.f / (float)((eh - sh) * (ew - sw)));
        }
    }
}

// ---------------- launch ----------------

extern "C" void kernel_launch(void* const* d_in, const int* in_sizes, int n_in,
                              void* d_out, int out_size, void* d_ws, size_t ws_size,
                              hipStream_t stream) {
    const float* feat = (const float*)d_in[0];
    const float* cb   = (const float*)d_in[1];
    const float* phiw = (const float*)d_in[2];
    const float* phib = (const float*)d_in[3];
    float* out = (float*)d_out;
    float* wsf = (float*)d_ws;

    const int NE = B * C * HH * HH; // 1048576
    float* f_rest = wsf;
    float* f_hat  = wsf + NE;
    float* zA     = wsf + 2 * NE;
    float* zB     = wsf + 3 * NE;
    char*  tl     = (char*)(wsf + 4 * NE);
    double* c2d  = (double*)tl;                             // 32 KB
    float*  c2f  = (float*)(tl + (32 << 10));               // 16 KB
    float4* pk   = (float4*)(tl + (48 << 10));              // 4 MB
    unsigned short* cbh = (unsigned short*)(tl + (48 << 10) + (4 << 20));   // 256 KB
    unsigned short* cbl = (unsigned short*)(tl + (48 << 10) + (4 << 20) + (512 << 10));

    static const int PN_[10]   = {1, 2, 3, 4, 5, 6, 8, 10, 13, 16};
    static const int PI_[10]   = {0, 0, 1, 1, 1, 2, 2, 2, 3, 3};
    static const int OFF_[10]  = {0, 1, 5, 14, 30, 55, 91, 155, 255, 424};
    static const int NSEG_[10] = {32, 32, 32, 16, 16, 16, 8, 8, 8, 8};

    setup_kernel<<<dim3((NE + 255) / 256), dim3(256), 0, stream>>>(
        feat, f_rest, f_hat, cb, c2d, c2f, zA, cbh, cbl);

    for (int si = 0; si < 10; ++si) {
        int pn = PN_[si], npx = pn * pn;
        int tokens = B * npx;            // divisible by 64 at every stage
        int nseg = NSEG_[si];
        int nblk_tok = tokens / 64;      // 64 tokens per block (4 waves x 16)
        int nblk = nblk_tok * nseg;
        float* zin  = (si & 1) ? zB : zA;
        float* zout = (si & 1) ? zA : zB;

        scan_mfma_kernel<<<dim3(nblk), dim3(256), 0, stream>>>(
            zin, cbh, cbl, c2f, pk, npx, nseg, nblk_tok);

        int pn2 = (si < 9) ? PN_[si + 1] : 0;
        stage_tail_kernel<<<dim3(B * 4), dim3(256), 0, stream>>>(
            pk, zin, cb, c2d,
            phiw + PI_[si] * C * C * 9, phib + PI_[si] * C,
            f_hat, f_rest, out, zout, pn, OFF_[si], pn2, nseg);
    }
}

// Round 25
// 685.900 us; speedup vs baseline: 1.0598x; 1.0165x over previous
//
#include <hip/hip_runtime.h>

#define B 128
#define C 32
#define HH 16
#define V 4096
#define MARGIN 1e-4f

typedef __attribute__((ext_vector_type(8))) short bf16x8;
typedef __attribute__((ext_vector_type(4))) float f32x4;

// ---------------- helpers ----------------

__device__ __forceinline__ float cubicw(float t) {
    float at = fabsf(t);
    float at2 = at * at, at3 = at2 * at;
    if (at <= 1.f) return 1.25f * at3 - 2.25f * at2 + 1.f;
    if (at < 2.f)  return -0.75f * at3 + 3.75f * at2 - 6.f * at + 3.f;
    return 0.f;
}

__device__ __forceinline__ unsigned short f2bf_rne(float f) {
    unsigned int u = __float_as_uint(f);
    unsigned int r = (u + 0x7fffu + ((u >> 16) & 1u)) >> 16;
    return (unsigned short)r;
}
__device__ __forceinline__ float bf2f(unsigned short h) {
    return __uint_as_float(((unsigned int)h) << 16);
}

// ---------------- kernels ----------------

// setup: f_rest=feat, f_hat=0, c2 (fp64+fp32), stage-0 z, codebook bf16 hi/lo frag tables
__global__ void setup_kernel(const float* __restrict__ feat, float* __restrict__ f_rest,
                             float* __restrict__ f_hat, const float* __restrict__ cb,
                             double* __restrict__ c2d, float* __restrict__ c2f,
                             float* __restrict__ z0, unsigned short* __restrict__ cbh,
                             unsigned short* __restrict__ cbl) {
    int i = blockIdx.x * 256 + threadIdx.x;
    if (i < B * C * HH * HH) { f_rest[i] = feat[i]; f_hat[i] = 0.f; }
    if (i < V) {
        const float* p = cb + i * C;
        double s = 0.0;
        #pragma unroll
        for (int j = 0; j < C; ++j) { double d = (double)p[j]; s = fma(d, d, s); }
        c2d[i] = s;
        c2f[i] = (float)s;
    }
    if (i < B * C) {
        const float* p = feat + i * (HH * HH);
        float s = 0.f;
        for (int px = 0; px < HH * HH; ++px) s += p[px];
        z0[i] = s * (1.f / 256.f);
    }
    if (i < V * C) {
        int ii = i & 7, nn = (i >> 3) & 15, kb = (i >> 7) & 3, T = i >> 9;
        float val = cb[(T * 16 + nn) * C + kb * 8 + ii];
        unsigned short h = f2bf_rne(val);
        cbh[i] = h;
        cbl[i] = f2bf_rne(val - bf2f(h));
    }
}

// ---- MFMA top-2 scan v5 (R21, best-known): 16 tokens/wave -> per-thread state
// ~40 VGPR, fits the compiler's ~44-reg envelope; direct L2 B-loads, high
// occupancy (R23/R24 LDS-sharing variants: barrier+residency cost > L2 win). ----
__global__ __launch_bounds__(256) void scan_mfma_kernel(
    const float* __restrict__ z, const unsigned short* __restrict__ cbh,
    const unsigned short* __restrict__ cbl, const float* __restrict__ c2f,
    float4* __restrict__ pk, int npx, int nseg, int ngrp)
{
    int tid = threadIdx.x;
    int wave = tid >> 6, lane = tid & 63;
    int job = blockIdx.x * 4 + wave;
    int seg = job / ngrp, tokgrp = job - seg * ngrp;
    int cps = V / nseg;
    int total = B * npx;
    int tn = lane & 15, kb = lane >> 4;

    __shared__ float smb1[4][16 * 17];
    __shared__ float smb2[4][16 * 17];
    __shared__ int   smi1[4][16 * 17];

    // build this lane's A-fragment pair in registers (8 VGPR total)
    bf16x8 ah, al;
    {
        int tok = tokgrp * 16 + tn;
        int bq = tok / npx, n = tok - bq * npx;
        #pragma unroll
        for (int i = 0; i < 8; ++i) {
            float v = z[(bq * C + kb * 8 + i) * npx + n];
            unsigned short h = f2bf_rne(v);
            ah[i] = (short)h;
            al[i] = (short)f2bf_rne(v - bf2f(h));
        }
    }

    const bf16x8* ph = reinterpret_cast<const bf16x8*>(cbh);
    const bf16x8* pl = reinterpret_cast<const bf16x8*>(cbl);

    float b1[4], b2[4]; int i1[4];
    #pragma unroll
    for (int s = 0; s < 4; ++s) { b1[s] = 3e38f; b2[s] = 3e38f; i1[s] = 0; }

    int T0 = seg * (cps >> 4), nT = cps >> 4;
    #pragma unroll 1
    for (int t = 0; t < nT; ++t) {
        int T = T0 + t;
        bf16x8 bh = ph[(size_t)T * 64 + lane];
        bf16x8 bl = pl[(size_t)T * 64 + lane];
        float c2v = c2f[T * 16 + tn];

        f32x4 a0 = {0.f, 0.f, 0.f, 0.f};
        a0 = __builtin_amdgcn_mfma_f32_16x16x32_bf16(ah, bh, a0, 0, 0, 0);
        a0 = __builtin_amdgcn_mfma_f32_16x16x32_bf16(al, bh, a0, 0, 0, 0);
        a0 = __builtin_amdgcn_mfma_f32_16x16x32_bf16(ah, bl, a0, 0, 0, 0);
        a0 = __builtin_amdgcn_mfma_f32_16x16x32_bf16(al, bl, a0, 0, 0, 0);

        int code = T * 16 + tn;   // ascending with t -> strict < keeps lowest idx
        #pragma unroll
        for (int r = 0; r < 4; ++r) {
            float s0 = fmaf(-2.f, a0[r], c2v);
            if (s0 < b1[r]) { b2[r] = b1[r]; b1[r] = s0; i1[r] = code; }
            else if (s0 < b2[r]) { b2[r] = s0; }
        }
    }

    // lane holds top-2 (over codes === tn mod 16) for tokens kb*4+r
    #pragma unroll
    for (int r = 0; r < 4; ++r) {
        int tokl = kb * 4 + r;
        smb1[wave][tokl * 17 + tn] = b1[r];
        smb2[wave][tokl * 17 + tn] = b2[r];
        smi1[wave][tokl * 17 + tn] = i1[r];
    }
    __syncthreads();
    if (tid < 64) {
        int w = tid >> 4, tl = tid & 15;
        int jobw = blockIdx.x * 4 + w;
        int segw = jobw / ngrp, tgw = jobw - segw * ngrp;
        float gb1 = 3e38f, gb2 = 3e38f; int gi1 = 0;
        #pragma unroll
        for (int i = 0; i < 16; ++i) {
            float v1 = smb1[w][tl * 17 + i];
            int   ix = smi1[w][tl * 17 + i];
            if (v1 < gb1 || (v1 == gb1 && ix < gi1)) { gb2 = gb1; gb1 = v1; gi1 = ix; }
            else if (v1 < gb2) { gb2 = v1; }
            float v2 = smb2[w][tl * 17 + i];
            if (v2 < gb2) gb2 = v2;
        }
        int tok = tgw * 16 + tl;
        float4 o;
        o.x = gb1; o.y = gb2; o.z = __int_as_float(gi1); o.w = 0.f;
        pk[(size_t)segw * total + tok] = o;
    }
}

// fused tail v4 (R21, best-known) + pn==16 bicubic skip (identity: weights {0,1,0,0}).
// w staged in LDS early; packed 16B combine loads; 16-channel bicubic chunks.
// B*4 blocks, 8 out-ch each.
__global__ __launch_bounds__(256) void stage_tail_kernel(
    const float4* __restrict__ pk, const float* __restrict__ z,
    const float* __restrict__ cb, const double* __restrict__ c2d,
    const float* __restrict__ w, const float* __restrict__ bias,
    float* __restrict__ f_hat, float* __restrict__ f_rest,
    float* __restrict__ out, float* __restrict__ znext,
    int pn, int off, int pn2, int nseg)
{
    int bb = blockIdx.x >> 2;
    int og = (blockIdx.x & 3) * 8;
    int tid = threadIdx.x;
    int npx = pn * pn;
    int total = B * npx;

    __shared__ float A_s[32][257];
    __shared__ float Bc[16][257];
    __shared__ alignas(16) float w_s[8 * 384];
    __shared__ int idx_s[256];
    __shared__ int flist[256];
    __shared__ int fcnt;
    __shared__ double zsd[C];
    __shared__ double sred[256];
    __shared__ int sidx[256];
    __shared__ float wtab[16][4];
    __shared__ int   itab[16][4];
    float (*fh_s)[257] = &A_s[0];
    float (*fr_s)[257] = &A_s[8];

    float pf[8], pr[8];
    #pragma unroll
    for (int o = 0; o < 8; ++o) {
        int gi = (bb * 32 + og + o) * 256 + tid;
        pf[o] = f_hat[gi]; pr[o] = f_rest[gi];
    }
    for (int e = tid; e < 8 * 288; e += 256) {
        int o = e / 288, r = e - o * 288;
        w_s[o * 384 + (r / 9) * 12 + (r % 9)] = w[(size_t)og * 288 + e];
    }

    if (tid < 16) {
        float scale = (float)pn * (1.f / 16.f);
        float src = (tid + 0.5f) * scale - 0.5f;
        int fi = (int)floorf(src);
        float t = src - (float)fi;
        #pragma unroll
        for (int k = 0; k < 4; ++k) {
            wtab[tid][k] = cubicw((float)(k - 1) - t);
            itab[tid][k] = min(max(fi + k - 1, 0), pn - 1);
        }
    }
    if (tid == 0) fcnt = 0;
    __syncthreads();

    // combine per-segment top-2 (one 16B load per segment)
    if (tid < npx) {
        int tok = bb * npx + tid;
        float gb1 = 3e38f, gb2 = 3e38f; int gi1 = 0;
        for (int s = 0; s < nseg; ++s) {
            float4 e = pk[(size_t)s * total + tok];
            float v1 = e.x; int ix = __float_as_int(e.z);
            if (v1 < gb1 || (v1 == gb1 && ix < gi1)) { gb2 = gb1; gb1 = v1; gi1 = ix; }
            else if (v1 < gb2) { gb2 = v1; }
            if (e.y < gb2) gb2 = e.y;
        }
        idx_s[tid] = gi1;
        if (gb2 - gb1 < MARGIN) { int slot = atomicAdd(&fcnt, 1); flist[slot] = tid; }
    }
    __syncthreads();

    // exact fp64 rescan for ambiguous tokens (rare)
    int nf = fcnt;
    for (int f = 0; f < nf; ++f) {
        int n = flist[f];
        if (tid < C) zsd[tid] = (double)z[(bb * C + tid) * npx + n];
        __syncthreads();
        double best = 1e300; int bi = 0x7fffffff;
        for (int k = 0; k < V / 256; ++k) {
            int v = tid + k * 256;
            const float4* cp = reinterpret_cast<const float4*>(cb + (size_t)v * C);
            double acc = 0.0;
            #pragma unroll
            for (int qq = 0; qq < 8; ++qq) {
                float4 fv = cp[qq];
                acc = fma((double)fv.x, zsd[4 * qq + 0], acc);
                acc = fma((double)fv.y, zsd[4 * qq + 1], acc);
                acc = fma((double)fv.z, zsd[4 * qq + 2], acc);
                acc = fma((double)fv.w, zsd[4 * qq + 3], acc);
            }
            double s = fma(-2.0, acc, c2d[v]);
            if (s < best || (s == best && v < bi)) { best = s; bi = v; }
        }
        sred[tid] = best; sidx[tid] = bi;
        __syncthreads();
        for (int st = 128; st > 0; st >>= 1) {
            if (tid < st) {
                double o = sred[tid + st]; int oi = sidx[tid + st];
                double me = sred[tid];     int mi = sidx[tid];
                if (o < me || (o == me && oi < mi)) { sred[tid] = o; sidx[tid] = oi; }
            }
            __syncthreads();
        }
        if (tid == 0) idx_s[n] = sidx[0];
        __syncthreads();
    }
    __syncthreads();

    // gather all 32 channels: A_s[c][n] = cb[idx[n]][c]
    for (int e = tid; e < 32 * npx; e += 256) {
        int c = e & 31, n = e >> 5;
        A_s[c][n] = cb[idx_s[n] * 32 + c];
    }
    __syncthreads();

    // separable bicubic (skip at pn==16: exactly identity)
    if (pn < 16) {
        #pragma unroll 1
        for (int ch = 0; ch < 2; ++ch) {
            for (int e = tid; e < 16 * 16 * pn; e += 256) {
                int wx = e % pn; int rest = e / pn;
                int p = rest & 15, cl = rest >> 4;
                float s = 0.f;
                #pragma unroll
                for (int k = 0; k < 4; ++k)
                    s = fmaf(wtab[p][k], A_s[ch * 16 + cl][itab[p][k] * pn + wx], s);
                Bc[cl][p * pn + wx] = s;
            }
            __syncthreads();
            #pragma unroll
            for (int it = 0; it < 16; ++it) {
                int e = tid + it * 256;
                int q = e & 15, p = (e >> 4) & 15, cl = e >> 8;
                float s = 0.f;
                #pragma unroll
                for (int k = 0; k < 4; ++k)
                    s = fmaf(wtab[q][k], Bc[cl][p * pn + itab[q][k]], s);
                A_s[ch * 16 + cl][e & 255] = s;
            }
            __syncthreads();
        }
    }

    // conv 3x3 SAME over 32 in-ch (A_s = hu) for out-ch og..og+7; w via LDS broadcast
    int p = tid >> 4, q = tid & 15;
    float acc[8];
    #pragma unroll
    for (int o = 0; o < 8; ++o) acc[o] = bias[og + o];
    for (int i = 0; i < 32; ++i) {
        float v[9];
        #pragma unroll
        for (int dy = 0; dy < 3; ++dy)
            #pragma unroll
            for (int dx = 0; dx < 3; ++dx) {
                int pp = p + dy - 1, qq = q + dx - 1;
                bool in = (pp >= 0) & (pp < 16) & (qq >= 0) & (qq < 16);
                v[dy * 3 + dx] = in ? A_s[i][pp * 16 + qq] : 0.f;
            }
        #pragma unroll
        for (int o = 0; o < 8; ++o) {
            const float* wr = &w_s[o * 384 + i * 12];
            float4 wa = *reinterpret_cast<const float4*>(wr);
            float4 wb = *reinterpret_cast<const float4*>(wr + 4);
            float w8 = wr[8];
            acc[o] = fmaf(wa.x, v[0], acc[o]); acc[o] = fmaf(wa.y, v[1], acc[o]);
            acc[o] = fmaf(wa.z, v[2], acc[o]); acc[o] = fmaf(wa.w, v[3], acc[o]);
            acc[o] = fmaf(wb.x, v[4], acc[o]); acc[o] = fmaf(wb.y, v[5], acc[o]);
            acc[o] = fmaf(wb.z, v[6], acc[o]); acc[o] = fmaf(wb.w, v[7], acc[o]);
            acc[o] = fmaf(w8,   v[8], acc[o]);
        }
    }
    float hv[8];
    #pragma unroll
    for (int o = 0; o < 8; ++o) hv[o] = A_s[og + o][tid];
    __syncthreads();   // all A_s reads done before overlay writes

    #pragma unroll
    for (int o = 0; o < 8; ++o) {
        int gi = (bb * 32 + og + o) * 256 + tid;
        float blend = 0.5f * hv[o] + 0.5f * acc[o];
        float nf2 = pf[o] + blend;
        float nr2 = pr[o] - blend;
        f_hat[gi] = nf2; f_rest[gi] = nr2;
        fh_s[o][tid] = nf2; fr_s[o][tid] = nr2;
    }
    __syncthreads();

    for (int e = tid; e < 8 * npx; e += 256) {
        int o = e & 7, n = e >> 3;
        int y = n / pn, x = n - y * pn;
        int sh = (y * HH) / pn, eh = ((y + 1) * HH + pn - 1) / pn;
        int sw = (x * HH) / pn, ew = ((x + 1) * HH + pn - 1) / pn;
        float s = 0.f;
        for (int yy = sh; yy < eh; ++yy)
            for (int xx = sw; xx < ew; ++xx) s += fh_s[o][yy * 16 + xx];
        out[((bb * 680) + off + n) * 32 + og + o] = s * (1.f / (float)((eh - sh) * (ew - sw)));
    }

    if (pn2 > 0) {
        int npx2 = pn2 * pn2;
        for (int e = tid; e < 8 * npx2; e += 256) {
            int o = e / npx2, n = e - o * npx2;
            int y = n / pn2, x = n - y * pn2;
            int sh = (y * HH) / pn2, eh = ((y + 1) * HH + pn2 - 1) / pn2;
            int sw = (x * HH) / pn2, ew = ((x + 1) * HH + pn2 - 1) / pn2;
            float s = 0.f;
            for (int yy = sh; yy < eh; ++yy)
                for (int xx = sw; xx < ew; ++xx) s += fr_s[o][yy * 16 + xx];
            znext[(bb * 32 + og + o) * npx2 + n] = s * (1.f / (float)((eh - sh) * (ew - sw)));
        }
    }
}

// ---------------- launch ----------------

extern "C" void kernel_launch(void* const* d_in, const int* in_sizes, int n_in,
                              void* d_out, int out_size, void* d_ws, size_t ws_size,
                              hipStream_t stream) {
    const float* feat = (const float*)d_in[0];
    const float* cb   = (const float*)d_in[1];
    const float* phiw = (const float*)d_in[2];
    const float* phib = (const float*)d_in[3];
    float* out = (float*)d_out;
    float* wsf = (float*)d_ws;

    const int NE = B * C * HH * HH; // 1048576
    float* f_rest = wsf;
    float* f_hat  = wsf + NE;
    float* zA     = wsf + 2 * NE;
    float* zB     = wsf + 3 * NE;
    char*  tl     = (char*)(wsf + 4 * NE);
    double* c2d  = (double*)tl;                             // 32 KB
    float*  c2f  = (float*)(tl + (32 << 10));               // 16 KB
    float4* pk   = (float4*)(tl + (48 << 10));              // 4 MB
    unsigned short* cbh = (unsigned short*)(tl + (48 << 10) + (4 << 20));   // 256 KB
    unsigned short* cbl = (unsigned short*)(tl + (48 << 10) + (4 << 20) + (512 << 10));

    static const int PN_[10]   = {1, 2, 3, 4, 5, 6, 8, 10, 13, 16};
    static const int PI_[10]   = {0, 0, 1, 1, 1, 2, 2, 2, 3, 3};
    static const int OFF_[10]  = {0, 1, 5, 14, 30, 55, 91, 155, 255, 424};
    static const int NSEG_[10] = {32, 32, 32, 16, 16, 16, 8, 8, 8, 8};

    setup_kernel<<<dim3((NE + 255) / 256), dim3(256), 0, stream>>>(
        feat, f_rest, f_hat, cb, c2d, c2f, zA, cbh, cbl);

    for (int si = 0; si < 10; ++si) {
        int pn = PN_[si], npx = pn * pn;
        int tokens = B * npx;
        int nseg = NSEG_[si];
        int ngrp = tokens / 16;
        int njobs = ngrp * nseg;         // divisible by 4 at every stage
        float* zin  = (si & 1) ? zB : zA;
        float* zout = (si & 1) ? zA : zB;

        scan_mfma_kernel<<<dim3(njobs / 4), dim3(256), 0, stream>>>(
            zin, cbh, cbl, c2f, pk, npx, nseg, ngrp);

        int pn2 = (si < 9) ? PN_[si + 1] : 0;
        stage_tail_kernel<<<dim3(B * 4), dim3(256), 0, stream>>>(
            pk, zin, cb, c2d,
            phiw + PI_[si] * C * C * 9, phib + PI_[si] * C,
            f_hat, f_rest, out, zout, pn, OFF_[si], pn2, nseg);
    }
}